// Round 19
// baseline (148.621 us; speedup 1.0000x reference)
//
#include <hip/hip_runtime.h>
#include <cstdint>
#include <cstddef>

// ---------------------------------------------------------------
// SparseAttention: B=2 L=4096 D=1024 H=16 HD=64 BS=64 NB=64 MAXB=11
// ---------------------------------------------------------------

#define MAXB 11
#define NT   16    // K-tiles: K=1024 / BK=64

typedef __attribute__((ext_vector_type(8))) short short8;
typedef __attribute__((ext_vector_type(4))) float f32x4;
typedef __attribute__((ext_vector_type(16))) float f32x16;

#define MFMA16(a, b, c) __builtin_amdgcn_mfma_f32_16x16x32_bf16((a), (b), (c), 0, 0, 0)
#define MFMA32(a, b, c) __builtin_amdgcn_mfma_f32_32x32x16_bf16((a), (b), (c), 0, 0, 0)

#define QSCALE 0.18033688011112042f   // 0.125 * log2(e)
#define LOG2E  1.44269504089f

#define BAR()   asm volatile("s_barrier" ::: "memory")
#define LGKM0() asm volatile("s_waitcnt lgkmcnt(0)" ::: "memory")
#define SCHED0() __builtin_amdgcn_sched_barrier(0)
#define VMC8()  asm volatile("s_waitcnt vmcnt(8)" ::: "memory")
#define VMC0()  asm volatile("s_waitcnt vmcnt(0)" ::: "memory")

__device__ __forceinline__ ushort f2bf(float f) {
  uint32_t u = __float_as_uint(f);
  u += 0x7FFFu + ((u >> 16) & 1u);   // RNE
  return (ushort)(u >> 16);
}

__device__ __forceinline__ uint32_t cvt_pk_bf16(float lo, float hi) {
  uint32_t r;
  asm("v_cvt_pk_bf16_f32 %0, %1, %2" : "=v"(r) : "v"(lo), "v"(hi));
  return r;
}

__device__ __forceinline__ void gload_lds16(const ushort* g, ushort* l) {
  __builtin_amdgcn_global_load_lds((const __attribute__((address_space(1))) void*)g,
                                   (__attribute__((address_space(3))) void*)l, 16, 0, 0);
}

// ---------------- fused f32 -> bf16 conversion (hidden + all 4 weights) ----------------
__global__ __launch_bounds__(256) void cvt_all(const float* __restrict__ hs,
                                               const float* __restrict__ wq,
                                               const float* __restrict__ wk,
                                               const float* __restrict__ wv,
                                               const float* __restrict__ wo,
                                               ushort* __restrict__ xb,
                                               ushort* __restrict__ wqkv,
                                               ushort* __restrict__ wob) {
  const int i = blockIdx.x * 256 + threadIdx.x;   // 0 .. 3,145,727 float4 units
  if (i < 2097152) {
    const float4 v = reinterpret_cast<const float4*>(hs)[i];
    ushort4 o;
    o.x = f2bf(v.x); o.y = f2bf(v.y); o.z = f2bf(v.z); o.w = f2bf(v.w);
    reinterpret_cast<ushort4*>(xb)[i] = o;
  } else {
    const int j = i - 2097152;
    const int part = j >> 18;
    const int k = j & 262143;
    const float* src = (part == 0) ? wq : (part == 1) ? wk : (part == 2) ? wv : wo;
    const float4 v = reinterpret_cast<const float4*>(src)[k];
    ushort4 o;
    o.x = f2bf(v.x); o.y = f2bf(v.y); o.z = f2bf(v.z); o.w = f2bf(v.w);
    if (part < 3) reinterpret_cast<ushort4*>(wqkv)[part * 262144 + k] = o;
    else          reinterpret_cast<ushort4*>(wob)[k] = o;
  }
}

// ---------------- 128x128 / 4-wave / 2-blocks-per-CU GEMM mainloop ----------------
// (round-16 structure, measured best: qkv 57.5us, MfmaUtil ~36% == m97 ceiling)
#define GA_(buf) ((buf) * 8192)
#define GB_(buf) (16384 + (buf) * 8192)

__device__ __forceinline__ void gemm4_mainloop(const ushort* __restrict__ Ag,
                                               const ushort* __restrict__ Bg,
                                               int m0, int n0,
                                               ushort* smem, f32x4 acc[4][4]) {
  const int tid = threadIdx.x;
  const int w = tid >> 6, lane = tid & 63;
  const int g = (lane >> 4) & 3, c = lane & 15;
  const int wm = w >> 1, wn = w & 1;
  const int rr = tid >> 3;                    // 0..31
  const int jj = (tid & 7) ^ (rr & 7);
  const int ca0 = g ^ (c & 7);
  const int ca1 = (4 + g) ^ (c & 7);

  auto stA = [&](int t) {                     // 4 chunks/thread (16KB tile)
    #pragma unroll
    for (int i = 0; i < 4; ++i)
      gload_lds16(Ag + (size_t)(m0 + i * 32 + rr) * 1024 + t * 64 + jj * 8,
                  smem + GA_(t & 1) + (i * 256 + w * 64) * 8);
  };
  auto stB = [&](int t) {
    #pragma unroll
    for (int i = 0; i < 4; ++i)
      gload_lds16(Bg + (size_t)(n0 + i * 32 + rr) * 1024 + t * 64 + jj * 8,
                  smem + GB_(t & 1) + (i * 256 + w * 64) * 8);
  };
  auto rdA = [&](int buf, int R, int cc) -> short8 {
    return *(const short8*)(smem + GA_(buf) + R * 64 + cc * 8);
  };
  auto rdB = [&](int buf, int R, int cc) -> short8 {
    return *(const short8*)(smem + GB_(buf) + R * 64 + cc * 8);
  };

  stA(0); stB(0);
  VMC0();
  BAR();

  short8 Af[4][2], Bf[4][2];
  #pragma unroll 2
  for (int t = 0; t < NT; ++t) {
    const int buf = t & 1;
    if (t + 1 < NT) { stA(t + 1); stB(t + 1); }   // into buf^1
    #pragma unroll
    for (int mi = 0; mi < 4; ++mi) {
      const int R = wm * 64 + mi * 16 + c;
      Af[mi][0] = rdA(buf, R, ca0);
      Af[mi][1] = rdA(buf, R, ca1);
    }
    #pragma unroll
    for (int ni = 0; ni < 4; ++ni) {
      const int R = wn * 64 + ni * 16 + c;
      Bf[ni][0] = rdB(buf, R, ca0);
      Bf[ni][1] = rdB(buf, R, ca1);
    }
    LGKM0(); SCHED0();
    __builtin_amdgcn_s_setprio(1);
    #pragma unroll
    for (int mi = 0; mi < 4; ++mi)
      #pragma unroll
      for (int ni = 0; ni < 4; ++ni)
        acc[mi][ni] = MFMA16(Af[mi][0], Bf[ni][0], acc[mi][ni]);
    #pragma unroll
    for (int mi = 0; mi < 4; ++mi)
      #pragma unroll
      for (int ni = 0; ni < 4; ++ni)
        acc[mi][ni] = MFMA16(Af[mi][1], Bf[ni][1], acc[mi][ni]);
    __builtin_amdgcn_s_setprio(0);
    if (t + 1 < NT) VMC0();
    BAR();
  }
}

// ---------------- GEMM1: QKV projection, 128x128, scatter epilogue ----------------
// XCD slab = 8 bm x 24 bn, as 3 supertiles of 8x8 = one concurrent round each;
// per-round working set A 2MB + B 2MB = 4MB = L2.
__global__ __launch_bounds__(256, 2) void gemm_qkv(const ushort* __restrict__ Xb,
                                                   const ushort* __restrict__ W,
                                                   ushort* __restrict__ Qb,
                                                   ushort* __restrict__ Kb,
                                                   ushort* __restrict__ Vtb) {
  __shared__ ushort smem[32768];   // 64 KB
  const int id  = blockIdx.x;                   // 1536 blocks
  const int xcd = id & 7;
  const int r   = id >> 3;                      // 0..191
  const int st  = r >> 6;                       // supertile 0..2
  const int u   = r & 63;
  const int bm  = xcd * 8 + (u & 7);            // 0..63
  const int bn  = st * 8 + (u >> 3);            // 0..23
  const int m0 = bm * 128, n0 = bn * 128;
  f32x4 acc[4][4] = {};
  gemm4_mainloop(Xb, W, m0, n0, smem, acc);

  const int tid = threadIdx.x;
  const int w = tid >> 6, lane = tid & 63;
  const int g = (lane >> 4) & 3, c = lane & 15;
  const int wm = w >> 1, wn = w & 1;
  #pragma unroll
  for (int mi = 0; mi < 4; ++mi) {
    #pragma unroll
    for (int ni = 0; ni < 4; ++ni) {
      const int n = n0 + wn * 64 + ni * 16 + c;
      const int part = n >> 10;
      const int h = (n >> 6) & 15;
      const int hd = n & 63;
      const int mbase = m0 + wm * 64 + mi * 16 + g * 4;
      const int b = mbase >> 12;            // 4-row group never crosses b
      const int lp0 = mbase & 4095;
      if (part == 0) {
        #pragma unroll
        for (int r2 = 0; r2 < 4; ++r2)
          Qb[((size_t)((b << 4) + h) * 4096 + lp0 + r2) * 64 + hd] =
              f2bf(acc[mi][ni][r2] * QSCALE);
      } else if (part == 1) {
        #pragma unroll
        for (int r2 = 0; r2 < 4; ++r2)
          Kb[((size_t)((b << 4) + h) * 4096 + lp0 + r2) * 64 + hd] =
              f2bf(acc[mi][ni][r2]);
      } else {
        uint2 pk;
        pk.x = cvt_pk_bf16(acc[mi][ni][0], acc[mi][ni][1]);
        pk.y = cvt_pk_bf16(acc[mi][ni][2], acc[mi][ni][3]);
        *(uint2*)&Vtb[((size_t)((b << 4) + h) * 64 + hd) * 4096 + lp0] = pk;
      }
    }
  }
}

// ---------------- GEMM2: output projection, 128x128, f32 store ----------------
__global__ __launch_bounds__(256, 2) void gemm_out(const ushort* __restrict__ X2,
                                                   const ushort* __restrict__ W,
                                                   float* __restrict__ out) {
  __shared__ ushort smem[32768];   // 64 KB
  const int id  = blockIdx.x;                 // 512 blocks
  const int swz = (id & 7) * 64 + (id >> 3);  // XCD chunking (512%8==0)
  const int bm = swz >> 3, bn = swz & 7;
  const int m0 = bm * 128, n0 = bn * 128;
  f32x4 acc[4][4] = {};
  gemm4_mainloop(X2, W, m0, n0, smem, acc);

  const int tid = threadIdx.x;
  const int w = tid >> 6, lane = tid & 63;
  const int g = (lane >> 4) & 3, c = lane & 15;
  const int wm = w >> 1, wn = w & 1;
  #pragma unroll
  for (int mi = 0; mi < 4; ++mi) {
    #pragma unroll
    for (int ni = 0; ni < 4; ++ni) {
      const int n = n0 + wn * 64 + ni * 16 + c;
      #pragma unroll
      for (int r = 0; r < 4; ++r) {
        const int m = m0 + wm * 64 + mi * 16 + g * 4 + r;
        out[(size_t)m * 1024 + n] = acc[mi][ni][r];
      }
    }
  }
}

// ---------------- block-sparse flash attention: 32x32 MFMA + DOUBLE-BUFFERED staging ----------------
// r13 structure (2 waves x 32 q-rows, in-register P via cvt_pk+permlane32_swap,
// static-max softmax) + r12's proven dbuf shell: stage tile i+1 into buf^1,
// counted vmcnt(8) (8 loads/thread/tile -> tile i complete, i+1 in flight).
// LDS 32KB. ONLY delta vs r13/r18: the double buffer.
__global__ __launch_bounds__(128, 4) void attn_kernel(const ushort* __restrict__ Qb,
                                                      const ushort* __restrict__ Kb,
                                                      const ushort* __restrict__ Vt,
                                                      const int* __restrict__ bidx,
                                                      const float* __restrict__ slopes,
                                                      ushort* __restrict__ X2) {
  __shared__ __align__(16) ushort Ks[2][4096];   // [64 keys][64 d], chunk-swizzled
  __shared__ __align__(16) ushort Vs[2][4096];   // [64 d][64 keys], chunk-swizzled

  const int phys = blockIdx.x;
  const int bid  = (phys & 7) * 256 + (phys >> 3);   // XCD swizzle
  const int qb = bid & 63;
  const int bh = bid >> 6;
  const int hh = bh & 15;
  const int b  = bh >> 4;
  const int tid = threadIdx.x;
  const int wv = tid >> 6, lane = tid & 63;
  const int ql = lane & 31;            // this lane's q-row (within wave tile)
  const int h2 = lane >> 5;            // half: splits k-dim of fragments
  const float slope = slopes[hh] * LOG2E;

  const int qrow = qb * 64 + wv * 32 + ql;           // global q position
  const ushort* qptr = Qb + ((size_t)bh * 4096 + qrow) * 64 + h2 * 8;
  short8 qf[4];
  #pragma unroll
  for (int dc = 0; dc < 4; ++dc) qf[dc] = *(const short8*)(qptr + dc * 16);

  const int* bl = bidx + qb * MAXB;

  // stage one 64-key block (K 8KB + V 8KB), 8 loads/thread (128 threads)
  auto stage = [&](int kb, int bufi) {
    #pragma unroll
    for (int j = 0; j < 4; ++j) {
      const int n = j * 128 + tid;                  // 16B-chunk 0..511
      const int row = n >> 3;
      const int sc = ((n & 7) ^ (row & 7)) * 8;
      gload_lds16(Kb + ((size_t)bh * 4096 + kb * 64 + row) * 64 + sc,
                  &Ks[bufi][0] + (j * 128 + (tid & ~63)) * 8);
    }
    #pragma unroll
    for (int j = 0; j < 4; ++j) {
      const int n = j * 128 + tid;
      const int row = n >> 3;                       // d index
      const int sc = ((n & 7) ^ (row & 7)) * 8;
      gload_lds16(Vt + ((size_t)bh * 64 + row) * 4096 + kb * 64 + sc,
                  &Vs[bufi][0] + (j * 128 + (tid & ~63)) * 8);
    }
  };

  f32x16 accO[2];                      // O^T d-halves: col=q=ql, row=(r&3)+8*(r>>2)+4*h2
  #pragma unroll
  for (int e = 0; e < 16; ++e) { accO[0][e] = 0.f; accO[1][e] = 0.f; }
  float lrun = 0.f;                    // partial denominator (own 32 keys/iter)
  const int qoff = qrow - 4 * h2;      // fold the +4*h2 key offset

  stage(bl[0], 0);                     // bl[0] always >= 0 (global blocks)

  #pragma unroll 1
  for (int i = 0; i < MAXB; ++i) {
    const int kb  = bl[i];                            // >= 0 on entry
    const int nkb = (i + 1 < MAXB) ? bl[i + 1] : -1;
    if (nkb >= 0) { stage(nkb, (i + 1) & 1); VMC8(); }  // tile i done; i+1 in flight
    else          { VMC0(); }
    BAR();                             // both waves see tile i
    const ushort* Kt = &Ks[i & 1][0];
    const ushort* Vv = &Vs[i & 1][0];

    // S^T = K * Q^T per key-half: 32k x 32q tiles, acc preloaded with -8
    f32x16 s2[2];
    #pragma unroll
    for (int kh = 0; kh < 2; ++kh) {
      f32x16 z;
      #pragma unroll
      for (int e = 0; e < 16; ++e) z[e] = -8.f;     // static-max fold
      #pragma unroll
      for (int dc = 0; dc < 4; ++dc) {
        const int row = kh * 32 + ql;
        const short8 kf = *(const short8*)(Kt + row * 64 +
                                           (((dc * 2 + h2) ^ (row & 7)) * 8));
        z = MFMA32(kf, qf[dc], z);
      }
      s2[kh] = z;
    }

    // ALiBi + exp2 (exp2 domain, fixed max); lane-local l accumulation
    const int ib = qoff - kb * 64;
    #pragma unroll
    for (int kh = 0; kh < 2; ++kh) {
      #pragma unroll
      for (int r = 0; r < 16; ++r) {
        const float dist = fabsf((float)(ib - kh * 32 - ((r & 3) + 8 * (r >> 2))));
        const float pv = __builtin_amdgcn_exp2f(fmaf(-slope, dist, s2[kh][r]));
        s2[kh][r] = pv;
        lrun += pv;
      }
    }

    // P -> bf16 B-fragments via cvt_pk + permlane32_swap (no LDS)
    short8 pfrag[4];
    #pragma unroll
    for (int kh = 0; kh < 2; ++kh) {
      #pragma unroll
      for (int half = 0; half < 2; ++half) {
        const int base = half * 8;
        uint32_t w0 = cvt_pk_bf16(s2[kh][base + 0], s2[kh][base + 1]);
        uint32_t w1 = cvt_pk_bf16(s2[kh][base + 2], s2[kh][base + 3]);
        uint32_t w2 = cvt_pk_bf16(s2[kh][base + 4], s2[kh][base + 5]);
        uint32_t w3 = cvt_pk_bf16(s2[kh][base + 6], s2[kh][base + 7]);
        asm volatile("v_permlane32_swap_b32 %0, %1" : "+v"(w0), "+v"(w2));
        asm volatile("v_permlane32_swap_b32 %0, %1" : "+v"(w1), "+v"(w3));
        uint32_t fr[4] = {w0, w1, w2, w3};
        pfrag[kh * 2 + half] = *(const short8*)fr;
      }
    }

    // O^T += V^T * P^T : per d-half dt, A = Vt rows dt*32+ql, 4 key-chunks
    #pragma unroll
    for (int dt = 0; dt < 2; ++dt) {
      #pragma unroll
      for (int kc = 0; kc < 4; ++kc) {
        const int row = dt * 32 + ql;
        const short8 vf = *(const short8*)(Vv + row * 64 +
                                           (((kc * 2 + h2) ^ (row & 7)) * 8));
        accO[dt] = MFMA32(vf, pfrag[kc], accO[dt]);
      }
    }
    BAR();                             // readers of buf i&1 done -> reusable
    if (nkb < 0) break;
  }

  // epilogue: full row denominator = own + partner half (same q, lane^32)
  float l = lrun + __shfl_xor(lrun, 32);
  const float rl = __builtin_amdgcn_rcpf(l);
  ushort* orow = X2 + ((size_t)b * 4096 + qrow) * 1024 + hh * 64;
  #pragma unroll
  for (int dt = 0; dt < 2; ++dt) {
    #pragma unroll
    for (int j = 0; j < 4; ++j) {
      uint2 pk;
      pk.x = cvt_pk_bf16(accO[dt][4 * j + 0] * rl, accO[dt][4 * j + 1] * rl);
      pk.y = cvt_pk_bf16(accO[dt][4 * j + 2] * rl, accO[dt][4 * j + 3] * rl);
      *(uint2*)(orow + dt * 32 + 8 * j + 4 * h2) = pk;
    }
  }
}

// ---------------- launch ----------------
extern "C" void kernel_launch(void* const* d_in, const int* in_sizes, int n_in,
                              void* d_out, int out_size, void* d_ws, size_t ws_size,
                              hipStream_t stream) {
  (void)in_sizes; (void)n_in; (void)out_size; (void)ws_size;
  const float* hs     = (const float*)d_in[0];
  const float* Wq     = (const float*)d_in[1];
  const float* Wk     = (const float*)d_in[2];
  const float* Wv     = (const float*)d_in[3];
  const float* Wo     = (const float*)d_in[4];
  const float* slopes = (const float*)d_in[5];
  const int*   bidx   = (const int*)d_in[6];
  float* out = (float*)d_out;

  char* ws = (char*)d_ws;
  ushort* Xb   = (ushort*)(ws + 0);             // 16 MB (dead after gemm_qkv; reused as X2)
  ushort* Wqkv = (ushort*)(ws + 16777216);      //  6 MB
  ushort* Wob  = (ushort*)(ws + 23068672);      //  2 MB
  ushort* Qb   = (ushort*)(ws + 25165824);      // 16 MB
  ushort* Kb   = (ushort*)(ws + 41943040);      // 16 MB
  ushort* Vtb  = (ushort*)(ws + 58720256);      // 16 MB ([B,H,64,L], written by gemm_qkv)
  ushort* X2   = Xb;

  cvt_all<<<12288, 256, 0, stream>>>(hs, Wq, Wk, Wv, Wo, Xb, Wqkv, Wob);

  gemm_qkv<<<1536, 256, 0, stream>>>(Xb, Wqkv, Qb, Kb, Vtb);
  attn_kernel<<<2048, 128, 0, stream>>>(Qb, Kb, Vtb, bidx, slopes, X2);
  gemm_out<<<512, 256, 0, stream>>>(X2, Wob, out);
}

// Round 20
// 136.508 us; speedup vs baseline: 1.0887x; 1.0887x over previous
//
#include <hip/hip_runtime.h>
#include <cstdint>
#include <cstddef>

// ---------------------------------------------------------------
// SparseAttention: B=2 L=4096 D=1024 H=16 HD=64 BS=64 NB=64 MAXB=11
// Round-18 configuration (measured best: 136.7 us) restored verbatim.
// ---------------------------------------------------------------

#define MAXB 11
#define NT   16    // K-tiles: K=1024 / BK=64

typedef __attribute__((ext_vector_type(8))) short short8;
typedef __attribute__((ext_vector_type(4))) float f32x4;
typedef __attribute__((ext_vector_type(16))) float f32x16;

#define MFMA16(a, b, c) __builtin_amdgcn_mfma_f32_16x16x32_bf16((a), (b), (c), 0, 0, 0)
#define MFMA32(a, b, c) __builtin_amdgcn_mfma_f32_32x32x16_bf16((a), (b), (c), 0, 0, 0)

#define QSCALE 0.18033688011112042f   // 0.125 * log2(e)
#define LOG2E  1.44269504089f

#define BAR()   asm volatile("s_barrier" ::: "memory")
#define LGKM0() asm volatile("s_waitcnt lgkmcnt(0)" ::: "memory")
#define SCHED0() __builtin_amdgcn_sched_barrier(0)
#define VMC0()  asm volatile("s_waitcnt vmcnt(0)" ::: "memory")

__device__ __forceinline__ ushort f2bf(float f) {
  uint32_t u = __float_as_uint(f);
  u += 0x7FFFu + ((u >> 16) & 1u);   // RNE
  return (ushort)(u >> 16);
}

__device__ __forceinline__ uint32_t cvt_pk_bf16(float lo, float hi) {
  uint32_t r;
  asm("v_cvt_pk_bf16_f32 %0, %1, %2" : "=v"(r) : "v"(lo), "v"(hi));
  return r;
}

__device__ __forceinline__ void gload_lds16(const ushort* g, ushort* l) {
  __builtin_amdgcn_global_load_lds((const __attribute__((address_space(1))) void*)g,
                                   (__attribute__((address_space(3))) void*)l, 16, 0, 0);
}

// ---------------- fused f32 -> bf16 conversion (hidden + all 4 weights) ----------------
__global__ __launch_bounds__(256) void cvt_all(const float* __restrict__ hs,
                                               const float* __restrict__ wq,
                                               const float* __restrict__ wk,
                                               const float* __restrict__ wv,
                                               const float* __restrict__ wo,
                                               ushort* __restrict__ xb,
                                               ushort* __restrict__ wqkv,
                                               ushort* __restrict__ wob) {
  const int i = blockIdx.x * 256 + threadIdx.x;   // 0 .. 3,145,727 float4 units
  if (i < 2097152) {
    const float4 v = reinterpret_cast<const float4*>(hs)[i];
    ushort4 o;
    o.x = f2bf(v.x); o.y = f2bf(v.y); o.z = f2bf(v.z); o.w = f2bf(v.w);
    reinterpret_cast<ushort4*>(xb)[i] = o;
  } else {
    const int j = i - 2097152;
    const int part = j >> 18;
    const int k = j & 262143;
    const float* src = (part == 0) ? wq : (part == 1) ? wk : (part == 2) ? wv : wo;
    const float4 v = reinterpret_cast<const float4*>(src)[k];
    ushort4 o;
    o.x = f2bf(v.x); o.y = f2bf(v.y); o.z = f2bf(v.z); o.w = f2bf(v.w);
    if (part < 3) reinterpret_cast<ushort4*>(wqkv)[part * 262144 + k] = o;
    else          reinterpret_cast<ushort4*>(wob)[k] = o;
  }
}

// ---------------- 128x128 / 4-wave / 2-blocks-per-CU GEMM mainloop ----------------
// (measured: qkv 57.5us @ MfmaUtil ~36% == the m97-structure ceiling)
#define GA_(buf) ((buf) * 8192)
#define GB_(buf) (16384 + (buf) * 8192)

__device__ __forceinline__ void gemm4_mainloop(const ushort* __restrict__ Ag,
                                               const ushort* __restrict__ Bg,
                                               int m0, int n0,
                                               ushort* smem, f32x4 acc[4][4]) {
  const int tid = threadIdx.x;
  const int w = tid >> 6, lane = tid & 63;
  const int g = (lane >> 4) & 3, c = lane & 15;
  const int wm = w >> 1, wn = w & 1;
  const int rr = tid >> 3;                    // 0..31
  const int jj = (tid & 7) ^ (rr & 7);
  const int ca0 = g ^ (c & 7);
  const int ca1 = (4 + g) ^ (c & 7);

  auto stA = [&](int t) {                     // 4 chunks/thread (16KB tile)
    #pragma unroll
    for (int i = 0; i < 4; ++i)
      gload_lds16(Ag + (size_t)(m0 + i * 32 + rr) * 1024 + t * 64 + jj * 8,
                  smem + GA_(t & 1) + (i * 256 + w * 64) * 8);
  };
  auto stB = [&](int t) {
    #pragma unroll
    for (int i = 0; i < 4; ++i)
      gload_lds16(Bg + (size_t)(n0 + i * 32 + rr) * 1024 + t * 64 + jj * 8,
                  smem + GB_(t & 1) + (i * 256 + w * 64) * 8);
  };
  auto rdA = [&](int buf, int R, int cc) -> short8 {
    return *(const short8*)(smem + GA_(buf) + R * 64 + cc * 8);
  };
  auto rdB = [&](int buf, int R, int cc) -> short8 {
    return *(const short8*)(smem + GB_(buf) + R * 64 + cc * 8);
  };

  stA(0); stB(0);
  VMC0();
  BAR();

  short8 Af[4][2], Bf[4][2];
  #pragma unroll 2
  for (int t = 0; t < NT; ++t) {
    const int buf = t & 1;
    if (t + 1 < NT) { stA(t + 1); stB(t + 1); }   // into buf^1
    #pragma unroll
    for (int mi = 0; mi < 4; ++mi) {
      const int R = wm * 64 + mi * 16 + c;
      Af[mi][0] = rdA(buf, R, ca0);
      Af[mi][1] = rdA(buf, R, ca1);
    }
    #pragma unroll
    for (int ni = 0; ni < 4; ++ni) {
      const int R = wn * 64 + ni * 16 + c;
      Bf[ni][0] = rdB(buf, R, ca0);
      Bf[ni][1] = rdB(buf, R, ca1);
    }
    LGKM0(); SCHED0();
    __builtin_amdgcn_s_setprio(1);
    #pragma unroll
    for (int mi = 0; mi < 4; ++mi)
      #pragma unroll
      for (int ni = 0; ni < 4; ++ni)
        acc[mi][ni] = MFMA16(Af[mi][0], Bf[ni][0], acc[mi][ni]);
    #pragma unroll
    for (int mi = 0; mi < 4; ++mi)
      #pragma unroll
      for (int ni = 0; ni < 4; ++ni)
        acc[mi][ni] = MFMA16(Af[mi][1], Bf[ni][1], acc[mi][ni]);
    __builtin_amdgcn_s_setprio(0);
    if (t + 1 < NT) VMC0();
    BAR();
  }
}

// ---------------- GEMM1: QKV projection, 128x128, scatter epilogue ----------------
// XCD slab = 8 bm x 24 bn, as 3 supertiles of 8x8 = one concurrent round each;
// per-round working set A 2MB + B 2MB = 4MB = L2.
__global__ __launch_bounds__(256, 2) void gemm_qkv(const ushort* __restrict__ Xb,
                                                   const ushort* __restrict__ W,
                                                   ushort* __restrict__ Qb,
                                                   ushort* __restrict__ Kb,
                                                   ushort* __restrict__ Vtb) {
  __shared__ ushort smem[32768];   // 64 KB
  const int id  = blockIdx.x;                   // 1536 blocks
  const int xcd = id & 7;
  const int r   = id >> 3;                      // 0..191
  const int st  = r >> 6;                       // supertile 0..2
  const int u   = r & 63;
  const int bm  = xcd * 8 + (u & 7);            // 0..63
  const int bn  = st * 8 + (u >> 3);            // 0..23
  const int m0 = bm * 128, n0 = bn * 128;
  f32x4 acc[4][4] = {};
  gemm4_mainloop(Xb, W, m0, n0, smem, acc);

  const int tid = threadIdx.x;
  const int w = tid >> 6, lane = tid & 63;
  const int g = (lane >> 4) & 3, c = lane & 15;
  const int wm = w >> 1, wn = w & 1;
  #pragma unroll
  for (int mi = 0; mi < 4; ++mi) {
    #pragma unroll
    for (int ni = 0; ni < 4; ++ni) {
      const int n = n0 + wn * 64 + ni * 16 + c;
      const int part = n >> 10;
      const int h = (n >> 6) & 15;
      const int hd = n & 63;
      const int mbase = m0 + wm * 64 + mi * 16 + g * 4;
      const int b = mbase >> 12;            // 4-row group never crosses b
      const int lp0 = mbase & 4095;
      if (part == 0) {
        #pragma unroll
        for (int r2 = 0; r2 < 4; ++r2)
          Qb[((size_t)((b << 4) + h) * 4096 + lp0 + r2) * 64 + hd] =
              f2bf(acc[mi][ni][r2] * QSCALE);
      } else if (part == 1) {
        #pragma unroll
        for (int r2 = 0; r2 < 4; ++r2)
          Kb[((size_t)((b << 4) + h) * 4096 + lp0 + r2) * 64 + hd] =
              f2bf(acc[mi][ni][r2]);
      } else {
        uint2 pk;
        pk.x = cvt_pk_bf16(acc[mi][ni][0], acc[mi][ni][1]);
        pk.y = cvt_pk_bf16(acc[mi][ni][2], acc[mi][ni][3]);
        *(uint2*)&Vtb[((size_t)((b << 4) + h) * 64 + hd) * 4096 + lp0] = pk;
      }
    }
  }
}

// ---------------- GEMM2: output projection, 128x128, f32 store ----------------
__global__ __launch_bounds__(256, 2) void gemm_out(const ushort* __restrict__ X2,
                                                   const ushort* __restrict__ W,
                                                   float* __restrict__ out) {
  __shared__ ushort smem[32768];   // 64 KB
  const int id  = blockIdx.x;                 // 512 blocks
  const int swz = (id & 7) * 64 + (id >> 3);  // XCD chunking (512%8==0)
  const int bm = swz >> 3, bn = swz & 7;
  const int m0 = bm * 128, n0 = bn * 128;
  f32x4 acc[4][4] = {};
  gemm4_mainloop(X2, W, m0, n0, smem, acc);

  const int tid = threadIdx.x;
  const int w = tid >> 6, lane = tid & 63;
  const int g = (lane >> 4) & 3, c = lane & 15;
  const int wm = w >> 1, wn = w & 1;
  #pragma unroll
  for (int mi = 0; mi < 4; ++mi) {
    #pragma unroll
    for (int ni = 0; ni < 4; ++ni) {
      const int n = n0 + wn * 64 + ni * 16 + c;
      #pragma unroll
      for (int r = 0; r < 4; ++r) {
        const int m = m0 + wm * 64 + mi * 16 + g * 4 + r;
        out[(size_t)m * 1024 + n] = acc[mi][ni][r];
      }
    }
  }
}

// ---------------- block-sparse flash attention: 32x32 MFMA, in-register P ----------------
// (round-13/18 version — single-buffered 16KB LDS, 8 blocks/CU; TLP across
//  co-resident blocks hides the stage latency. Measured best; dbuf regressed
//  it by cutting occupancy — r19.)
__global__ __launch_bounds__(128, 4) void attn_kernel(const ushort* __restrict__ Qb,
                                                      const ushort* __restrict__ Kb,
                                                      const ushort* __restrict__ Vt,
                                                      const int* __restrict__ bidx,
                                                      const float* __restrict__ slopes,
                                                      ushort* __restrict__ X2) {
  __shared__ __align__(16) ushort Ks[4096];      // [64 keys][64 d], chunk-swizzled
  __shared__ __align__(16) ushort Vs[4096];      // [64 d][64 keys], chunk-swizzled

  const int phys = blockIdx.x;
  const int bid  = (phys & 7) * 256 + (phys >> 3);   // XCD swizzle
  const int qb = bid & 63;
  const int bh = bid >> 6;
  const int hh = bh & 15;
  const int b  = bh >> 4;
  const int tid = threadIdx.x;
  const int wv = tid >> 6, lane = tid & 63;
  const int ql = lane & 31;            // this lane's q-row (within wave tile)
  const int h2 = lane >> 5;            // half: splits k-dim of fragments
  const float slope = slopes[hh] * LOG2E;

  const int qrow = qb * 64 + wv * 32 + ql;           // global q position
  const ushort* qptr = Qb + ((size_t)bh * 4096 + qrow) * 64 + h2 * 8;
  short8 qf[4];
  #pragma unroll
  for (int dc = 0; dc < 4; ++dc) qf[dc] = *(const short8*)(qptr + dc * 16);

  const int* bl = bidx + qb * MAXB;

  // stage one 64-key block (K 8KB + V 8KB), 8 loads/thread (128 threads)
  auto stage = [&](int kb) {
    #pragma unroll
    for (int j = 0; j < 4; ++j) {
      const int n = j * 128 + tid;                  // 16B-chunk 0..511
      const int row = n >> 3;
      const int sc = ((n & 7) ^ (row & 7)) * 8;
      gload_lds16(Kb + ((size_t)bh * 4096 + kb * 64 + row) * 64 + sc,
                  Ks + (j * 128 + (tid & ~63)) * 8);
    }
    #pragma unroll
    for (int j = 0; j < 4; ++j) {
      const int n = j * 128 + tid;
      const int row = n >> 3;                       // d index
      const int sc = ((n & 7) ^ (row & 7)) * 8;
      gload_lds16(Vt + ((size_t)bh * 64 + row) * 4096 + kb * 64 + sc,
                  Vs + (j * 128 + (tid & ~63)) * 8);
    }
  };

  f32x16 accO[2];                      // O^T d-halves: col=q=ql, row=(r&3)+8*(r>>2)+4*h2
  #pragma unroll
  for (int e = 0; e < 16; ++e) { accO[0][e] = 0.f; accO[1][e] = 0.f; }
  float lrun = 0.f;                    // partial denominator (own 32 keys/iter)
  const int qoff = qrow - 4 * h2;      // fold the +4*h2 key offset

  #pragma unroll 1
  for (int i = 0; i < MAXB; ++i) {
    const int kb = bl[i];                            // uniform
    if (kb < 0) break;
    stage(kb);
    VMC0();
    BAR();                             // both waves' loads visible

    // S^T = K * Q^T per key-half: 32k x 32q tiles, acc preloaded with -8
    f32x16 s2[2];
    #pragma unroll
    for (int kh = 0; kh < 2; ++kh) {
      f32x16 z;
      #pragma unroll
      for (int e = 0; e < 16; ++e) z[e] = -8.f;     // static-max fold
      #pragma unroll
      for (int dc = 0; dc < 4; ++dc) {
        const int row = kh * 32 + ql;
        const short8 kf = *(const short8*)(Ks + row * 64 +
                                           (((dc * 2 + h2) ^ (row & 7)) * 8));
        z = MFMA32(kf, qf[dc], z);
      }
      s2[kh] = z;
    }

    // ALiBi + exp2 (exp2 domain, fixed max); lane-local l accumulation
    const int ib = qoff - kb * 64;
    #pragma unroll
    for (int kh = 0; kh < 2; ++kh) {
      #pragma unroll
      for (int r = 0; r < 16; ++r) {
        const float dist = fabsf((float)(ib - kh * 32 - ((r & 3) + 8 * (r >> 2))));
        const float pv = __builtin_amdgcn_exp2f(fmaf(-slope, dist, s2[kh][r]));
        s2[kh][r] = pv;
        lrun += pv;
      }
    }

    // P -> bf16 B-fragments via cvt_pk + permlane32_swap (no LDS)
    short8 pfrag[4];
    #pragma unroll
    for (int kh = 0; kh < 2; ++kh) {
      #pragma unroll
      for (int half = 0; half < 2; ++half) {
        const int base = half * 8;
        uint32_t w0 = cvt_pk_bf16(s2[kh][base + 0], s2[kh][base + 1]);
        uint32_t w1 = cvt_pk_bf16(s2[kh][base + 2], s2[kh][base + 3]);
        uint32_t w2 = cvt_pk_bf16(s2[kh][base + 4], s2[kh][base + 5]);
        uint32_t w3 = cvt_pk_bf16(s2[kh][base + 6], s2[kh][base + 7]);
        asm volatile("v_permlane32_swap_b32 %0, %1" : "+v"(w0), "+v"(w2));
        asm volatile("v_permlane32_swap_b32 %0, %1" : "+v"(w1), "+v"(w3));
        uint32_t fr[4] = {w0, w1, w2, w3};
        pfrag[kh * 2 + half] = *(const short8*)fr;
      }
    }

    // O^T += V^T * P^T : per d-half dt, A = Vt rows dt*32+ql, 4 key-chunks
    #pragma unroll
    for (int dt = 0; dt < 2; ++dt) {
      #pragma unroll
      for (int kc = 0; kc < 4; ++kc) {
        const int row = dt * 32 + ql;
        const short8 vf = *(const short8*)(Vs + row * 64 +
                                           (((kc * 2 + h2) ^ (row & 7)) * 8));
        accO[dt] = MFMA32(vf, pfrag[kc], accO[dt]);
      }
    }
    BAR();                             // all reads done -> buffer reusable
  }

  // epilogue: full row denominator = own + partner half (same q, lane^32)
  float l = lrun + __shfl_xor(lrun, 32);
  const float rl = __builtin_amdgcn_rcpf(l);
  ushort* orow = X2 + ((size_t)b * 4096 + qrow) * 1024 + hh * 64;
  #pragma unroll
  for (int dt = 0; dt < 2; ++dt) {
    #pragma unroll
    for (int j = 0; j < 4; ++j) {
      uint2 pk;
      pk.x = cvt_pk_bf16(accO[dt][4 * j + 0] * rl, accO[dt][4 * j + 1] * rl);
      pk.y = cvt_pk_bf16(accO[dt][4 * j + 2] * rl, accO[dt][4 * j + 3] * rl);
      *(uint2*)(orow + dt * 32 + 8 * j + 4 * h2) = pk;
    }
  }
}

// ---------------- launch ----------------
extern "C" void kernel_launch(void* const* d_in, const int* in_sizes, int n_in,
                              void* d_out, int out_size, void* d_ws, size_t ws_size,
                              hipStream_t stream) {
  (void)in_sizes; (void)n_in; (void)out_size; (void)ws_size;
  const float* hs     = (const float*)d_in[0];
  const float* Wq     = (const float*)d_in[1];
  const float* Wk     = (const float*)d_in[2];
  const float* Wv     = (const float*)d_in[3];
  const float* Wo     = (const float*)d_in[4];
  const float* slopes = (const float*)d_in[5];
  const int*   bidx   = (const int*)d_in[6];
  float* out = (float*)d_out;

  char* ws = (char*)d_ws;
  ushort* Xb   = (ushort*)(ws + 0);             // 16 MB (dead after gemm_qkv; reused as X2)
  ushort* Wqkv = (ushort*)(ws + 16777216);      //  6 MB
  ushort* Wob  = (ushort*)(ws + 23068672);      //  2 MB
  ushort* Qb   = (ushort*)(ws + 25165824);      // 16 MB
  ushort* Kb   = (ushort*)(ws + 41943040);      // 16 MB
  ushort* Vtb  = (ushort*)(ws + 58720256);      // 16 MB ([B,H,64,L], written by gemm_qkv)
  ushort* X2   = Xb;

  cvt_all<<<12288, 256, 0, stream>>>(hs, Wq, Wk, Wv, Wo, Xb, Wqkv, Wob);

  gemm_qkv<<<1536, 256, 0, stream>>>(Xb, Wqkv, Qb, Kb, Vtb);
  attn_kernel<<<2048, 128, 0, stream>>>(Qb, Kb, Vtb, bidx, slopes, X2);
  gemm_out<<<512, 256, 0, stream>>>(X2, Wob, out);
}